// Round 1
// baseline (258.812 us; speedup 1.0000x reference)
//
#include <hip/hip_runtime.h>
#include <math.h>

#define EPS 1e-8f

constexpr int Bb = 8, Nn = 2048, Hh = 128;
constexpr int BN = Bb * Nn;  // 16384 rows per tensor

// ---------------------------------------------------------------------------
// Kernel 1: per-row inverse L2 norms. One wave (64 lanes) per 128-elem row.
// ---------------------------------------------------------------------------
__global__ __launch_bounds__(256) void norms_kernel(const float* __restrict__ h1,
                                                    const float* __restrict__ h2,
                                                    float* __restrict__ inv1,
                                                    float* __restrict__ inv2) {
  int wave = threadIdx.x >> 6;
  int lane = threadIdx.x & 63;
  int row = blockIdx.x * 4 + wave;            // 0 .. 2*BN-1
  const float* src = (row < BN) ? h1 : h2;
  float* dst = (row < BN) ? inv1 : inv2;
  int r = row & (BN - 1);
  const float* p = src + (size_t)r * Hh;
  float a = p[lane];
  float b = p[lane + 64];
  float ss = a * a + b * b;
  #pragma unroll
  for (int off = 32; off > 0; off >>= 1) ss += __shfl_down(ss, off, 64);
  if (lane == 0) dst[r] = 1.0f / fmaxf(sqrtf(ss), EPS);
}

// ---------------------------------------------------------------------------
// Kernel 2: W2T[l][k] = w_m[k][l]^2  (transposed so fm matvecs coalesce on k)
// ---------------------------------------------------------------------------
__global__ __launch_bounds__(256) void w2t_kernel(const float* __restrict__ wm,
                                                  float* __restrict__ w2t) {
  int idx = blockIdx.x * 256 + threadIdx.x;   // 0 .. 16383
  int l = idx >> 7, k = idx & 127;
  float v = wm[k * Hh + l];
  w2t[idx] = v * v;
}

// ---------------------------------------------------------------------------
// Kernel 3: M[mat][b][l][h]: mat=0 -> M1 = n1^T h1, mat=1 -> M2 = n2^T h2.
// grid = mat(2) x b(8) x chunk(16); chunk = 128 source rows.
// 8x8 register tile per thread; rank-8 updates from LDS; fp32 atomics out.
// ---------------------------------------------------------------------------
__global__ __launch_bounds__(256) void mat_kernel(const float* __restrict__ h1,
                                                  const float* __restrict__ h2,
                                                  const float* __restrict__ inv1,
                                                  const float* __restrict__ inv2,
                                                  float* __restrict__ M) {
  int idx = blockIdx.x;
  int chunk = idx & 15;
  int b = (idx >> 4) & 7;
  int mat = idx >> 7;
  const float* src = mat ? h2 : h1;
  const float* inv = mat ? inv2 : inv1;
  const float* rowbase = src + ((size_t)b * Nn + chunk * 128) * Hh;
  const float* invbase = inv + b * Nn + chunk * 128;

  __shared__ float rows[8][128];
  __shared__ float sinv[128];
  int t = threadIdx.x;
  if (t < 128) sinv[t] = invbase[t];

  int k0 = (t & 15) * 8;    // 16 k-groups
  int h0 = (t >> 4) * 8;    // 16 h-groups
  float acc[8][8];
  #pragma unroll
  for (int i = 0; i < 8; i++)
    #pragma unroll
    for (int m = 0; m < 8; m++) acc[i][m] = 0.0f;

  for (int j0 = 0; j0 < 128; j0 += 8) {
    __syncthreads();
    ((float4*)&rows[0][0])[t] = ((const float4*)(rowbase + (size_t)j0 * Hh))[t];
    __syncthreads();
    #pragma unroll
    for (int jj = 0; jj < 8; jj++) {
      float s = sinv[j0 + jj];
      float4 ka = *(const float4*)&rows[jj][k0];
      float4 kb = *(const float4*)&rows[jj][k0 + 4];
      float4 ha = *(const float4*)&rows[jj][h0];
      float4 hb = *(const float4*)&rows[jj][h0 + 4];
      float vk[8] = {s*ka.x, s*ka.y, s*ka.z, s*ka.w, s*kb.x, s*kb.y, s*kb.z, s*kb.w};
      float vh[8] = {ha.x, ha.y, ha.z, ha.w, hb.x, hb.y, hb.z, hb.w};
      #pragma unroll
      for (int i = 0; i < 8; i++)
        #pragma unroll
        for (int m = 0; m < 8; m++)
          acc[i][m] += vk[i] * vh[m];
    }
  }

  float* Mout = M + ((size_t)mat * Bb + b) * (Hh * Hh);
  #pragma unroll
  for (int i = 0; i < 8; i++)
    #pragma unroll
    for (int m = 0; m < 8; m++)
      atomicAdd(&Mout[(k0 + i) * Hh + h0 + m], acc[i][m]);
}

// ---------------------------------------------------------------------------
// Kernel 4: fused y = inv*(x @ M) then fm epilogue.
// grid = which(2) x b(8) x tile(64); 32 rows per block, 256 threads.
// which=0: x=h1, M=M2 (mat slot 1). which=1: x=h2, M=M1 (mat slot 0).
// ---------------------------------------------------------------------------
__global__ __launch_bounds__(256) void fused_kernel(const float* __restrict__ h1,
                                                    const float* __restrict__ h2,
                                                    const float* __restrict__ inv1,
                                                    const float* __restrict__ inv2,
                                                    const float* __restrict__ M,
                                                    const float* __restrict__ w2t,
                                                    float* __restrict__ out) {
  int idx = blockIdx.x;
  int tile = idx & 63;
  int b = (idx >> 6) & 7;
  int which = idx >> 9;
  const float* xsrc = which ? h2 : h1;
  const float* inv = which ? inv2 : inv1;
  const float* Mb = M + ((size_t)(which ^ 1) * Bb + b) * (Hh * Hh);
  int n0 = tile * 32;
  const float* xbase = xsrc + ((size_t)b * Nn + n0) * Hh;

  __shared__ float xs[32][128];
  __shared__ float ys[32][128];
  __shared__ float invs[32];
  int t = threadIdx.x;
  {
    const float4* g = (const float4*)xbase;
    float4* s4 = (float4*)&xs[0][0];
    #pragma unroll
    for (int i = 0; i < 4; i++) s4[t + 256 * i] = g[t + 256 * i];
    if (t < 32) invs[t] = inv[b * Nn + n0 + t];
  }
  __syncthreads();

  int k0 = (t & 31) * 4;   // 32 col-groups of 4
  int r0 = (t >> 5) * 4;   // 8 row-groups of 4

  // phase 1: ys = inv * (xs @ M)   (M rows stream through L1/L2)
  {
    float acc[4][4];
    #pragma unroll
    for (int j = 0; j < 4; j++)
      #pragma unroll
      for (int c = 0; c < 4; c++) acc[j][c] = 0.0f;
    for (int l = 0; l < 128; l++) {
      float4 m4 = *(const float4*)(Mb + (size_t)l * Hh + k0);
      float mc[4] = {m4.x, m4.y, m4.z, m4.w};
      float xv[4] = {xs[r0][l], xs[r0+1][l], xs[r0+2][l], xs[r0+3][l]};
      #pragma unroll
      for (int j = 0; j < 4; j++)
        #pragma unroll
        for (int c = 0; c < 4; c++)
          acc[j][c] += xv[j] * mc[c];
    }
    #pragma unroll
    for (int j = 0; j < 4; j++) {
      float s = invs[r0 + j];
      float4 o = {acc[j][0] * s, acc[j][1] * s, acc[j][2] * s, acc[j][3] * s};
      *(float4*)&ys[r0 + j][k0] = o;
    }
  }
  __syncthreads();

  // phase 2: num/dx2/dy2 matvecs against W2T + cosine epilogue
  float na[4][4], xa[4][4], ya[4][4];
  #pragma unroll
  for (int j = 0; j < 4; j++)
    #pragma unroll
    for (int c = 0; c < 4; c++) { na[j][c] = 0.f; xa[j][c] = 0.f; ya[j][c] = 0.f; }

  for (int l = 0; l < 128; l++) {
    float4 w4 = *(const float4*)(w2t + (size_t)l * Hh + k0);
    float wc[4] = {w4.x, w4.y, w4.z, w4.w};
    #pragma unroll
    for (int j = 0; j < 4; j++) {
      float xv = xs[r0 + j][l];
      float yv = ys[r0 + j][l];
      float pxy = xv * yv, pxx = xv * xv, pyy = yv * yv;
      #pragma unroll
      for (int c = 0; c < 4; c++) {
        na[j][c] += pxy * wc[c];
        xa[j][c] += pxx * wc[c];
        ya[j][c] += pyy * wc[c];
      }
    }
  }

  float* obase = out + (((size_t)which * Bb + b) * Nn + n0) * Hh;
  #pragma unroll
  for (int j = 0; j < 4; j++) {
    float4 o;
    float* oc = (float*)&o;
    #pragma unroll
    for (int c = 0; c < 4; c++) {
      float dx = fmaxf(sqrtf(xa[j][c]), EPS);
      float dy = fmaxf(sqrtf(ya[j][c]), EPS);
      oc[c] = na[j][c] / (dx * dy);
    }
    *(float4*)&obase[(size_t)(r0 + j) * Hh + k0] = o;
  }
}

// ---------------------------------------------------------------------------
extern "C" void kernel_launch(void* const* d_in, const int* in_sizes, int n_in,
                              void* d_out, int out_size, void* d_ws, size_t ws_size,
                              hipStream_t stream) {
  const float* h1 = (const float*)d_in[0];
  const float* h2 = (const float*)d_in[1];
  const float* wm = (const float*)d_in[2];
  float* out = (float*)d_out;

  float* ws = (float*)d_ws;
  float* inv1 = ws;                 // 16384
  float* inv2 = ws + 16384;         // 16384
  float* w2t  = ws + 32768;         // 16384
  float* M    = ws + 49152;         // 2*8*128*128 = 262144

  hipMemsetAsync(M, 0, (size_t)2 * Bb * Hh * Hh * sizeof(float), stream);
  norms_kernel<<<2 * BN / 4, 256, 0, stream>>>(h1, h2, inv1, inv2);
  w2t_kernel<<<Hh * Hh / 256, 256, 0, stream>>>(wm, w2t);
  mat_kernel<<<2 * Bb * 16, 256, 0, stream>>>(h1, h2, inv1, inv2, M);
  fused_kernel<<<2 * Bb * 64, 256, 0, stream>>>(h1, h2, inv1, inv2, M, w2t, out);
}

// Round 2
// 185.397 us; speedup vs baseline: 1.3960x; 1.3960x over previous
//
#include <hip/hip_runtime.h>
#include <math.h>

#define EPS 1e-8f

constexpr int Bb = 8, Nn = 2048, Hh = 128;
constexpr int BN = Bb * Nn;  // 16384 rows per tensor

// ---------------------------------------------------------------------------
// Kernel 1: per-row inverse L2 norms. One wave (64 lanes) per 128-elem row.
// ---------------------------------------------------------------------------
__global__ __launch_bounds__(256) void norms_kernel(const float* __restrict__ h1,
                                                    const float* __restrict__ h2,
                                                    float* __restrict__ inv1,
                                                    float* __restrict__ inv2) {
  int wave = threadIdx.x >> 6;
  int lane = threadIdx.x & 63;
  int row = blockIdx.x * 4 + wave;            // 0 .. 2*BN-1
  const float* src = (row < BN) ? h1 : h2;
  float* dst = (row < BN) ? inv1 : inv2;
  int r = row & (BN - 1);
  const float* p = src + (size_t)r * Hh;
  float a = p[lane];
  float b = p[lane + 64];
  float ss = a * a + b * b;
  #pragma unroll
  for (int off = 32; off > 0; off >>= 1) ss += __shfl_down(ss, off, 64);
  if (lane == 0) dst[r] = 1.0f / fmaxf(sqrtf(ss), EPS);
}

// ---------------------------------------------------------------------------
// Kernel 2: W2T[l][k] = w_m[k][l]^2  (transposed so fm matvecs coalesce on k)
// ---------------------------------------------------------------------------
__global__ __launch_bounds__(256) void w2t_kernel(const float* __restrict__ wm,
                                                  float* __restrict__ w2t) {
  int idx = blockIdx.x * 256 + threadIdx.x;   // 0 .. 16383
  int l = idx >> 7, k = idx & 127;
  float v = wm[k * Hh + l];
  w2t[idx] = v * v;
}

// ---------------------------------------------------------------------------
// Kernel 3a: split-K partials. grid = (mat x b)(16) x nchunks blocks.
// Each block: 128x128 partial over rowsPerChunk source rows, plain stores.
// mat=0 -> M1 = n1^T h1, mat=1 -> M2 = n2^T h2.
// ---------------------------------------------------------------------------
__global__ __launch_bounds__(256) void matp_kernel(const float* __restrict__ h1,
                                                   const float* __restrict__ h2,
                                                   const float* __restrict__ inv1,
                                                   const float* __restrict__ inv2,
                                                   float* __restrict__ Mpart,
                                                   int nchunks, int rowsPerChunk) {
  int idx = blockIdx.x;
  int chunk = idx % nchunks;
  int mb = idx / nchunks;        // 0..15
  int b = mb & 7;
  int mat = mb >> 3;
  const float* src = mat ? h2 : h1;
  const float* inv = mat ? inv2 : inv1;
  int row0 = chunk * rowsPerChunk;
  const float* rowbase = src + ((size_t)b * Nn + row0) * Hh;
  const float* invbase = inv + b * Nn + row0;

  __shared__ float rows[8][128];
  __shared__ float sinv[8];
  int t = threadIdx.x;

  int k0 = (t & 15) * 8;    // 16 k-groups
  int h0 = (t >> 4) * 8;    // 16 h-groups
  float acc[8][8];
  #pragma unroll
  for (int i = 0; i < 8; i++)
    #pragma unroll
    for (int m = 0; m < 8; m++) acc[i][m] = 0.0f;

  for (int j0 = 0; j0 < rowsPerChunk; j0 += 8) {
    __syncthreads();
    ((float4*)&rows[0][0])[t] = ((const float4*)(rowbase + (size_t)j0 * Hh))[t];
    if (t < 8) sinv[t] = invbase[j0 + t];
    __syncthreads();
    #pragma unroll
    for (int jj = 0; jj < 8; jj++) {
      float s = sinv[jj];
      float4 ka = *(const float4*)&rows[jj][k0];
      float4 kb = *(const float4*)&rows[jj][k0 + 4];
      float4 ha = *(const float4*)&rows[jj][h0];
      float4 hb = *(const float4*)&rows[jj][h0 + 4];
      float vk[8] = {s*ka.x, s*ka.y, s*ka.z, s*ka.w, s*kb.x, s*kb.y, s*kb.z, s*kb.w};
      float vh[8] = {ha.x, ha.y, ha.z, ha.w, hb.x, hb.y, hb.z, hb.w};
      #pragma unroll
      for (int i = 0; i < 8; i++)
        #pragma unroll
        for (int m = 0; m < 8; m++)
          acc[i][m] += vk[i] * vh[m];
    }
  }

  float* Mout = Mpart + (size_t)idx * (Hh * Hh);
  #pragma unroll
  for (int i = 0; i < 8; i++) {
    float4 lo = {acc[i][0], acc[i][1], acc[i][2], acc[i][3]};
    float4 hi = {acc[i][4], acc[i][5], acc[i][6], acc[i][7]};
    *(float4*)&Mout[(k0 + i) * Hh + h0] = lo;
    *(float4*)&Mout[(k0 + i) * Hh + h0 + 4] = hi;
  }
}

// ---------------------------------------------------------------------------
// Kernel 3b: reduce partials over chunks. One float4 per thread.
// Mpart layout: [mb(16)][chunk(nchunks)][16384]; M: [mb][16384].
// ---------------------------------------------------------------------------
__global__ __launch_bounds__(256) void matr_kernel(const float* __restrict__ Mpart,
                                                   float* __restrict__ M,
                                                   int nchunks) {
  int gid = blockIdx.x * 256 + threadIdx.x;   // 0..65535 float4 units
  int mb = gid >> 12;                          // 4096 float4 per matrix
  int i4 = gid & 4095;
  const float4* p = (const float4*)Mpart + ((size_t)mb * nchunks) * 4096 + i4;
  float4 s = {0.f, 0.f, 0.f, 0.f};
  for (int c = 0; c < nchunks; c++) {
    float4 v = p[(size_t)c * 4096];
    s.x += v.x; s.y += v.y; s.z += v.z; s.w += v.w;
  }
  ((float4*)M)[gid] = s;
}

// ---------------------------------------------------------------------------
// Kernel 4: fused y = inv*(x @ M) then fm epilogue.
// grid = which(2) x b(8) x tile(64); 32 rows per block, 256 threads.
// which=0: x=h1, M=M2 (mat slot 1). which=1: x=h2, M=M1 (mat slot 0).
// ---------------------------------------------------------------------------
__global__ __launch_bounds__(256) void fused_kernel(const float* __restrict__ h1,
                                                    const float* __restrict__ h2,
                                                    const float* __restrict__ inv1,
                                                    const float* __restrict__ inv2,
                                                    const float* __restrict__ M,
                                                    const float* __restrict__ w2t,
                                                    float* __restrict__ out) {
  int idx = blockIdx.x;
  int tile = idx & 63;
  int b = (idx >> 6) & 7;
  int which = idx >> 9;
  const float* xsrc = which ? h2 : h1;
  const float* inv = which ? inv2 : inv1;
  const float* Mb = M + ((size_t)(which ^ 1) * Bb + b) * (Hh * Hh);
  int n0 = tile * 32;
  const float* xbase = xsrc + ((size_t)b * Nn + n0) * Hh;

  __shared__ float xs[32][128];
  __shared__ float ys[32][128];
  __shared__ float invs[32];
  int t = threadIdx.x;
  {
    const float4* g = (const float4*)xbase;
    float4* s4 = (float4*)&xs[0][0];
    #pragma unroll
    for (int i = 0; i < 4; i++) s4[t + 256 * i] = g[t + 256 * i];
    if (t < 32) invs[t] = inv[b * Nn + n0 + t];
  }
  __syncthreads();

  int k0 = (t & 31) * 4;   // 32 col-groups of 4
  int r0 = (t >> 5) * 4;   // 8 row-groups of 4

  // phase 1: ys = inv * (xs @ M)   (M rows stream through L1/L2)
  {
    float acc[4][4];
    #pragma unroll
    for (int j = 0; j < 4; j++)
      #pragma unroll
      for (int c = 0; c < 4; c++) acc[j][c] = 0.0f;
    for (int l = 0; l < 128; l++) {
      float4 m4 = *(const float4*)(Mb + (size_t)l * Hh + k0);
      float mc[4] = {m4.x, m4.y, m4.z, m4.w};
      float xv[4] = {xs[r0][l], xs[r0+1][l], xs[r0+2][l], xs[r0+3][l]};
      #pragma unroll
      for (int j = 0; j < 4; j++)
        #pragma unroll
        for (int c = 0; c < 4; c++)
          acc[j][c] += xv[j] * mc[c];
    }
    #pragma unroll
    for (int j = 0; j < 4; j++) {
      float s = invs[r0 + j];
      float4 o = {acc[j][0] * s, acc[j][1] * s, acc[j][2] * s, acc[j][3] * s};
      *(float4*)&ys[r0 + j][k0] = o;
    }
  }
  __syncthreads();

  // phase 2: num/dx2/dy2 matvecs against W2T + cosine epilogue
  float na[4][4], xa[4][4], ya[4][4];
  #pragma unroll
  for (int j = 0; j < 4; j++)
    #pragma unroll
    for (int c = 0; c < 4; c++) { na[j][c] = 0.f; xa[j][c] = 0.f; ya[j][c] = 0.f; }

  for (int l = 0; l < 128; l++) {
    float4 w4 = *(const float4*)(w2t + (size_t)l * Hh + k0);
    float wc[4] = {w4.x, w4.y, w4.z, w4.w};
    #pragma unroll
    for (int j = 0; j < 4; j++) {
      float xv = xs[r0 + j][l];
      float yv = ys[r0 + j][l];
      float pxy = xv * yv, pxx = xv * xv, pyy = yv * yv;
      #pragma unroll
      for (int c = 0; c < 4; c++) {
        na[j][c] += pxy * wc[c];
        xa[j][c] += pxx * wc[c];
        ya[j][c] += pyy * wc[c];
      }
    }
  }

  float* obase = out + (((size_t)which * Bb + b) * Nn + n0) * Hh;
  #pragma unroll
  for (int j = 0; j < 4; j++) {
    float4 o;
    float* oc = (float*)&o;
    #pragma unroll
    for (int c = 0; c < 4; c++) {
      float dx = fmaxf(sqrtf(xa[j][c]), EPS);
      float dy = fmaxf(sqrtf(ya[j][c]), EPS);
      oc[c] = na[j][c] / (dx * dy);
    }
    *(float4*)&obase[(size_t)(r0 + j) * Hh + k0] = o;
  }
}

// ---------------------------------------------------------------------------
extern "C" void kernel_launch(void* const* d_in, const int* in_sizes, int n_in,
                              void* d_out, int out_size, void* d_ws, size_t ws_size,
                              hipStream_t stream) {
  const float* h1 = (const float*)d_in[0];
  const float* h2 = (const float*)d_in[1];
  const float* wm = (const float*)d_in[2];
  float* out = (float*)d_out;

  float* ws = (float*)d_ws;
  float* inv1 = ws;                 // 16384
  float* inv2 = ws + 16384;         // 16384
  float* w2t  = ws + 32768;         // 16384
  float* M    = ws + 49152;         // 2*8*128*128 = 262144
  float* Mpart = ws + 49152 + 262144;

  // pick split-K chunk count that fits the workspace (16*C*16384 floats)
  size_t avail_floats = ws_size / 4;
  avail_floats = (avail_floats > 49152 + 262144) ? avail_floats - (49152 + 262144) : 0;
  int C = 64;
  while (C > 1 && (size_t)16 * C * 16384 > avail_floats) C >>= 1;

  norms_kernel<<<2 * BN / 4, 256, 0, stream>>>(h1, h2, inv1, inv2);
  w2t_kernel<<<Hh * Hh / 256, 256, 0, stream>>>(wm, w2t);

  if ((size_t)16 * 16384 > avail_floats) {
    // degenerate fallback: no room for partials — compute directly into M (C=1)
    matp_kernel<<<16, 256, 0, stream>>>(h1, h2, inv1, inv2, M, 1, Nn);
  } else {
    matp_kernel<<<16 * C, 256, 0, stream>>>(h1, h2, inv1, inv2, Mpart, C, Nn / C);
    matr_kernel<<<(16 * Hh * Hh / 4) / 256, 256, 0, stream>>>(Mpart, M, C);
  }

  fused_kernel<<<2 * Bb * 64, 256, 0, stream>>>(h1, h2, inv1, inv2, M, w2t, out);
}

// Round 3
// 148.401 us; speedup vs baseline: 1.7440x; 1.2493x over previous
//
#include <hip/hip_runtime.h>
#include <hip/hip_bf16.h>
#include <math.h>

#define EPS 1e-8f

constexpr int Bb = 8, Nn = 2048, Hh = 128;
constexpr int BN = Bb * Nn;  // 16384 rows per tensor

typedef __attribute__((ext_vector_type(8))) short bf16x8;
typedef __attribute__((ext_vector_type(4))) float f32x4;

#define MFMA16(a, b, c) __builtin_amdgcn_mfma_f32_16x16x32_bf16(a, b, c, 0, 0, 0)

static __device__ __forceinline__ ushort f2bf(float f) {
  union { __hip_bfloat16 h; ushort s; } u;
  u.h = __float2bfloat16(f);   // RNE
  return u.s;
}
static __device__ __forceinline__ float bf2f(ushort s) {
  union { float f; uint u; } u;
  u.u = ((uint)s) << 16;
  return u.f;
}
static __device__ __forceinline__ bf16x8 cvt8(const float* v) {
  bf16x8 r;
  #pragma unroll
  for (int i = 0; i < 4; i++) {
    union { __hip_bfloat162 h; short2 s; } u;
    u.h = __float22bfloat162_rn(make_float2(v[2 * i], v[2 * i + 1]));
    r[2 * i] = u.s.x; r[2 * i + 1] = u.s.y;
  }
  return r;
}
static __device__ __forceinline__ void split8(const float* v, bf16x8& hi, bf16x8& lo) {
  hi = cvt8(v);
  float res[8];
  #pragma unroll
  for (int i = 0; i < 8; i++) res[i] = v[i] - bf2f((ushort)hi[i]);
  lo = cvt8(res);
}

// ---------------------------------------------------------------------------
// Kernel 1: per-row inverse L2 norms. One wave per 128-elem row.
// ---------------------------------------------------------------------------
__global__ __launch_bounds__(256) void norms_kernel(const float* __restrict__ h1,
                                                    const float* __restrict__ h2,
                                                    float* __restrict__ inv1,
                                                    float* __restrict__ inv2) {
  int wave = threadIdx.x >> 6;
  int lane = threadIdx.x & 63;
  int row = blockIdx.x * 4 + wave;
  const float* src = (row < BN) ? h1 : h2;
  float* dst = (row < BN) ? inv1 : inv2;
  int r = row & (BN - 1);
  const float* p = src + (size_t)r * Hh;
  float a = p[lane];
  float b = p[lane + 64];
  float ss = a * a + b * b;
  #pragma unroll
  for (int off = 32; off > 0; off >>= 1) ss += __shfl_down(ss, off, 64);
  if (lane == 0) dst[r] = 1.0f / fmaxf(sqrtf(ss), EPS);
}

// ---------------------------------------------------------------------------
// Kernel 2: W2 split to bf16 hi/lo, layout [k][l] (== wm layout, squared)
// ---------------------------------------------------------------------------
__global__ __launch_bounds__(256) void w2split_kernel(const float* __restrict__ wm,
                                                      ushort* __restrict__ W2h,
                                                      ushort* __restrict__ W2l) {
  int idx = blockIdx.x * 256 + threadIdx.x;   // 0..16383
  float w = wm[idx];
  float v = w * w;
  ushort hi = f2bf(v);
  W2h[idx] = hi;
  W2l[idx] = f2bf(v - bf2f(hi));
}

// ---------------------------------------------------------------------------
// Kernel 3a: split-K partials (fp32). grid = (mat x b)(16) x nchunks.
// mat=0 -> M1 = n1^T h1, mat=1 -> M2 = n2^T h2.
// ---------------------------------------------------------------------------
__global__ __launch_bounds__(256) void matp_kernel(const float* __restrict__ h1,
                                                   const float* __restrict__ h2,
                                                   const float* __restrict__ inv1,
                                                   const float* __restrict__ inv2,
                                                   float* __restrict__ Mpart,
                                                   int nchunks, int rowsPerChunk) {
  int idx = blockIdx.x;
  int chunk = idx % nchunks;
  int mb = idx / nchunks;        // 0..15
  int b = mb & 7;
  int mat = mb >> 3;
  const float* src = mat ? h2 : h1;
  const float* inv = mat ? inv2 : inv1;
  int row0 = chunk * rowsPerChunk;
  const float* rowbase = src + ((size_t)b * Nn + row0) * Hh;
  const float* invbase = inv + b * Nn + row0;

  __shared__ float rows[8][128];
  __shared__ float sinv[8];
  int t = threadIdx.x;

  int k0 = (t & 15) * 8;
  int h0 = (t >> 4) * 8;
  float acc[8][8];
  #pragma unroll
  for (int i = 0; i < 8; i++)
    #pragma unroll
    for (int m = 0; m < 8; m++) acc[i][m] = 0.0f;

  for (int j0 = 0; j0 < rowsPerChunk; j0 += 8) {
    __syncthreads();
    ((float4*)&rows[0][0])[t] = ((const float4*)(rowbase + (size_t)j0 * Hh))[t];
    if (t < 8) sinv[t] = invbase[j0 + t];
    __syncthreads();
    #pragma unroll
    for (int jj = 0; jj < 8; jj++) {
      float s = sinv[jj];
      float4 ka = *(const float4*)&rows[jj][k0];
      float4 kb = *(const float4*)&rows[jj][k0 + 4];
      float4 ha = *(const float4*)&rows[jj][h0];
      float4 hb = *(const float4*)&rows[jj][h0 + 4];
      float vk[8] = {s*ka.x, s*ka.y, s*ka.z, s*ka.w, s*kb.x, s*kb.y, s*kb.z, s*kb.w};
      float vh[8] = {ha.x, ha.y, ha.z, ha.w, hb.x, hb.y, hb.z, hb.w};
      #pragma unroll
      for (int i = 0; i < 8; i++)
        #pragma unroll
        for (int m = 0; m < 8; m++)
          acc[i][m] += vk[i] * vh[m];
    }
  }

  float* Mout = Mpart + (size_t)idx * (Hh * Hh);
  #pragma unroll
  for (int i = 0; i < 8; i++) {
    float4 lo = {acc[i][0], acc[i][1], acc[i][2], acc[i][3]};
    float4 hi = {acc[i][4], acc[i][5], acc[i][6], acc[i][7]};
    *(float4*)&Mout[(k0 + i) * Hh + h0] = lo;
    *(float4*)&Mout[(k0 + i) * Hh + h0 + 4] = hi;
  }
}

// ---------------------------------------------------------------------------
// Kernel 3b: reduce partials -> transposed split-bf16 MT[mb][h][l].
// Mpart layout: [mb(16)][chunk(nchunks)][l(128)][h(128)].
// ---------------------------------------------------------------------------
__global__ __launch_bounds__(256) void matr_kernel(const float* __restrict__ Mpart,
                                                   ushort* __restrict__ MTh,
                                                   ushort* __restrict__ MTl,
                                                   int nchunks) {
  int gid = blockIdx.x * 256 + threadIdx.x;   // 0..65535 float4 units
  int mb = gid >> 12;
  int i4 = gid & 4095;
  int l = i4 >> 5, h0 = (i4 & 31) * 4;
  const float4* p = (const float4*)Mpart + (size_t)mb * nchunks * 4096 + i4;
  float4 s = {0.f, 0.f, 0.f, 0.f};
  for (int c = 0; c < nchunks; c++) {
    float4 v = p[(size_t)c * 4096];
    s.x += v.x; s.y += v.y; s.z += v.z; s.w += v.w;
  }
  float sv[4] = {s.x, s.y, s.z, s.w};
  ushort* oh = MTh + (size_t)mb * 16384;
  ushort* ol = MTl + (size_t)mb * 16384;
  #pragma unroll
  for (int i = 0; i < 4; i++) {
    float v = sv[i];
    ushort hi = f2bf(v);
    oh[(h0 + i) * 128 + l] = hi;
    ol[(h0 + i) * 128 + l] = f2bf(v - bf2f(hi));
  }
}

// ---------------------------------------------------------------------------
// Kernel 4: MFMA fused kernel. 64 rows/block, 4 waves x 16-row tiles.
// Phase 1: y = (x @ M) * inv  (split-bf16, 3 passes)
// Phase 2: num (3 passes), dx2/dy2 (2 passes) vs split W2; cosine epilogue.
// ---------------------------------------------------------------------------
__global__ __launch_bounds__(256, 2) void fusedm_kernel(
    const float* __restrict__ h1, const float* __restrict__ h2,
    const float* __restrict__ inv1, const float* __restrict__ inv2,
    const ushort* __restrict__ MTh, const ushort* __restrict__ MTl,
    const ushort* __restrict__ W2h, const ushort* __restrict__ W2l,
    float* __restrict__ out) {
  constexpr int LD = 132;  // +4 pad: float4-aligned, banks spread, 2-way max
  __shared__ float xs[64 * LD];
  __shared__ float ys[64 * LD];
  __shared__ float invs[64];

  int g0 = blockIdx.x * 64;            // row in [0, 32768)
  int which = g0 >> 14;
  int b = (g0 >> 11) & 7;
  int n0 = g0 & 2047;
  const float* xsrc = which ? h2 : h1;
  const float* invp = which ? inv2 : inv1;
  const ushort* Bh = MTh + (size_t)((which ^ 1) * 8 + b) * 16384;
  const ushort* Bl = MTl + (size_t)((which ^ 1) * 8 + b) * 16384;

  int t = threadIdx.x;
  {
    const float4* g = (const float4*)(xsrc + ((size_t)b * Nn + n0) * Hh);
    #pragma unroll
    for (int i = 0; i < 8; i++) {
      int u = t + 256 * i;             // float4 id 0..2047
      int r = u >> 5, c = (u & 31) << 2;
      *(float4*)&xs[r * LD + c] = g[u];
    }
    if (t < 64) invs[t] = invp[b * Nn + n0 + t];
  }
  __syncthreads();

  int lane = t & 63;
  int m = lane & 15, q = lane >> 4;    // A row (m), k-octet (q)
  int rb = (t >> 6) * 16;              // wave's first row

  // ---- phase 1 ----
  f32x4 acc1[8];
  #pragma unroll
  for (int nt = 0; nt < 8; nt++) acc1[nt] = (f32x4){0.f, 0.f, 0.f, 0.f};
  #pragma unroll
  for (int ks = 0; ks < 4; ks++) {
    int k0 = ks * 32 + q * 8;
    float xv[8];
    *(float4*)&xv[0] = *(const float4*)&xs[(rb + m) * LD + k0];
    *(float4*)&xv[4] = *(const float4*)&xs[(rb + m) * LD + k0 + 4];
    bf16x8 xh, xl;
    split8(xv, xh, xl);
    #pragma unroll
    for (int nt = 0; nt < 8; nt++) {
      int bo = (nt * 16 + m) * 128 + k0;
      bf16x8 fh = *(const bf16x8*)(Bh + bo);
      bf16x8 fl = *(const bf16x8*)(Bl + bo);
      acc1[nt] = MFMA16(xh, fh, acc1[nt]);
      acc1[nt] = MFMA16(xh, fl, acc1[nt]);
      acc1[nt] = MFMA16(xl, fh, acc1[nt]);
    }
  }
  // y -> LDS (C layout: col = lane&15, row = q*4+reg); own rows only
  #pragma unroll
  for (int nt = 0; nt < 8; nt++)
    #pragma unroll
    for (int rg = 0; rg < 4; rg++) {
      int row = rb + q * 4 + rg;
      ys[row * LD + nt * 16 + m] = acc1[nt][rg] * invs[row];
    }

  // ---- phase 2 (same-wave LDS dep only; no barrier) ----
  f32x4 aN[8], aX[8], aY[8];
  #pragma unroll
  for (int nt = 0; nt < 8; nt++) {
    aN[nt] = (f32x4){0.f, 0.f, 0.f, 0.f};
    aX[nt] = (f32x4){0.f, 0.f, 0.f, 0.f};
    aY[nt] = (f32x4){0.f, 0.f, 0.f, 0.f};
  }
  #pragma unroll
  for (int ks = 0; ks < 4; ks++) {
    int k0 = ks * 32 + q * 8;
    float xv[8], yv[8], pxy[8], pxx[8], pyy[8];
    *(float4*)&xv[0] = *(const float4*)&xs[(rb + m) * LD + k0];
    *(float4*)&xv[4] = *(const float4*)&xs[(rb + m) * LD + k0 + 4];
    *(float4*)&yv[0] = *(const float4*)&ys[(rb + m) * LD + k0];
    *(float4*)&yv[4] = *(const float4*)&ys[(rb + m) * LD + k0 + 4];
    #pragma unroll
    for (int i = 0; i < 8; i++) {
      pxy[i] = xv[i] * yv[i];
      pxx[i] = xv[i] * xv[i];
      pyy[i] = yv[i] * yv[i];
    }
    bf16x8 xyh, xyl;
    split8(pxy, xyh, xyl);
    bf16x8 xxh = cvt8(pxx);
    bf16x8 yyh = cvt8(pyy);
    #pragma unroll
    for (int nt = 0; nt < 8; nt++) {
      int bo = (nt * 16 + m) * 128 + k0;
      bf16x8 wh = *(const bf16x8*)(W2h + bo);
      bf16x8 wl = *(const bf16x8*)(W2l + bo);
      aN[nt] = MFMA16(xyh, wh, aN[nt]);
      aN[nt] = MFMA16(xyh, wl, aN[nt]);
      aN[nt] = MFMA16(xyl, wh, aN[nt]);
      aX[nt] = MFMA16(xxh, wh, aX[nt]);
      aX[nt] = MFMA16(xxh, wl, aX[nt]);
      aY[nt] = MFMA16(yyh, wh, aY[nt]);
      aY[nt] = MFMA16(yyh, wl, aY[nt]);
    }
  }
  // epilogue
  float* ob = out + (((size_t)which * Bb + b) * Nn + n0) * Hh;
  #pragma unroll
  for (int nt = 0; nt < 8; nt++)
    #pragma unroll
    for (int rg = 0; rg < 4; rg++) {
      int row = rb + q * 4 + rg;
      float dx2 = fmaxf(aX[nt][rg], 0.f);   // guard tiny negatives from lo-pass
      float dy2 = fmaxf(aY[nt][rg], 0.f);
      float dx = fmaxf(sqrtf(dx2), EPS);
      float dy = fmaxf(sqrtf(dy2), EPS);
      ob[(size_t)row * Hh + nt * 16 + m] = aN[nt][rg] / (dx * dy);
    }
}

// ---------------------------------------------------------------------------
extern "C" void kernel_launch(void* const* d_in, const int* in_sizes, int n_in,
                              void* d_out, int out_size, void* d_ws, size_t ws_size,
                              hipStream_t stream) {
  const float* h1 = (const float*)d_in[0];
  const float* h2 = (const float*)d_in[1];
  const float* wm = (const float*)d_in[2];
  float* out = (float*)d_out;

  char* ws = (char*)d_ws;
  float* inv1  = (float*)ws;                    // 65536 B
  float* inv2  = (float*)(ws + 65536);          // 65536 B
  ushort* W2h  = (ushort*)(ws + 131072);        // 32768 B
  ushort* W2l  = (ushort*)(ws + 163840);        // 32768 B
  ushort* MTh  = (ushort*)(ws + 196608);        // 524288 B
  ushort* MTl  = (ushort*)(ws + 720896);        // 524288 B
  float* Mpart = (float*)(ws + 1245184);

  size_t avail = (ws_size > 1245184) ? ws_size - 1245184 : 0;
  int C = 32;
  while (C > 1 && (size_t)C * 16 * Hh * Hh * 4 > avail) C >>= 1;

  norms_kernel<<<2 * BN / 4, 256, 0, stream>>>(h1, h2, inv1, inv2);
  w2split_kernel<<<Hh * Hh / 256, 256, 0, stream>>>(wm, W2h, W2l);
  matp_kernel<<<16 * C, 256, 0, stream>>>(h1, h2, inv1, inv2, Mpart, C, Nn / C);
  matr_kernel<<<(16 * Hh * Hh / 4) / 256, 256, 0, stream>>>(Mpart, MTh, MTl, C);
  fusedm_kernel<<<2 * BN / 64, 256, 0, stream>>>(h1, h2, inv1, inv2, MTh, MTl, W2h, W2l, out);
}

// Round 4
// 107.822 us; speedup vs baseline: 2.4004x; 1.3764x over previous
//
#include <hip/hip_runtime.h>
#include <hip/hip_bf16.h>
#include <math.h>

#define EPS 1e-8f

constexpr int Bb = 8, Nn = 2048, Hh = 128;
constexpr int BN = Bb * Nn;      // 16384 rows per tensor
constexpr int CCH = 16;          // split-K chunks for matp

typedef __attribute__((ext_vector_type(8))) short bf16x8;
typedef __attribute__((ext_vector_type(4))) float f32x4;

#define MFMA16(a, b, c) __builtin_amdgcn_mfma_f32_16x16x32_bf16(a, b, c, 0, 0, 0)

static __device__ __forceinline__ ushort f2bf(float f) {
  union { __hip_bfloat16 h; ushort s; } u;
  u.h = __float2bfloat16(f);   // RNE
  return u.s;
}
static __device__ __forceinline__ float bf2f(ushort s) {
  union { float f; uint u; } u;
  u.u = ((uint)s) << 16;
  return u.f;
}
static __device__ __forceinline__ bf16x8 cvt8(const float* v) {
  bf16x8 r;
  #pragma unroll
  for (int i = 0; i < 4; i++) {
    union { __hip_bfloat162 h; short2 s; } u;
    u.h = __float22bfloat162_rn(make_float2(v[2 * i], v[2 * i + 1]));
    r[2 * i] = u.s.x; r[2 * i + 1] = u.s.y;
  }
  return r;
}
static __device__ __forceinline__ void split8(const float* v, bf16x8& hi, bf16x8& lo) {
  hi = cvt8(v);
  float res[8];
  #pragma unroll
  for (int i = 0; i < 8; i++) res[i] = v[i] - bf2f((ushort)hi[i]);
  lo = cvt8(res);
}

// ---------------------------------------------------------------------------
// Kernel 1: W2i[k][0..127]=hi(wm[k][l]^2), [k][128..255]=lo  (LDS-ready)
// ---------------------------------------------------------------------------
__global__ __launch_bounds__(256) void w2i_kernel(const float* __restrict__ wm,
                                                  ushort* __restrict__ W2i) {
  int idx = blockIdx.x * 256 + threadIdx.x;   // k*128+h
  int k = idx >> 7, h = idx & 127;
  float w = wm[idx];
  float v = w * w;
  ushort hi = f2bf(v);
  W2i[k * 256 + h] = hi;
  W2i[k * 256 + 128 + h] = f2bf(v - bf2f(hi));
}

// ---------------------------------------------------------------------------
// Kernel 2: matp — M = (s.h)^T (s.h) per (mat,b), split-K chunk of 128 rows.
// Computes inv inline, builds transposed split-bf16 T in LDS (stride 264
// ushorts: +8 pad -> 2-way bank aliasing only), 3-pass MFMA, fp32 partials.
// grid: idx = mb*CCH + chunk, mb = mat*8+b.
// ---------------------------------------------------------------------------
__global__ __launch_bounds__(256) void matp_kernel(const float* __restrict__ h1,
                                                   const float* __restrict__ h2,
                                                   float* __restrict__ inv_out,
                                                   float* __restrict__ Mpart) {
  int idx = blockIdx.x;
  int chunk = idx % CCH;
  int mb = idx / CCH;
  int b = mb & 7;
  int mat = mb >> 3;
  const float* src = (mat ? h2 : h1) + ((size_t)b * Nn + chunk * 128) * Hh;
  float* invp = inv_out + mat * BN + b * Nn + chunk * 128;

  __shared__ float xs[64 * 132];     // 64-row staging, padded
  __shared__ ushort T[128 * 264];    // [col c][hi n 0..127 | lo n 128..255 | pad]
  __shared__ float sS[128];          // sqrt(inv) per row
  int t = threadIdx.x;

  for (int half = 0; half < 2; half++) {
    __syncthreads();
    #pragma unroll
    for (int i = 0; i < 8; i++) {
      int u = t + 256 * i;                 // 0..2047 float4 units
      int r = u >> 5, c = (u & 31) << 2;
      *(float4*)&xs[r * 132 + c] = *(const float4*)(src + (size_t)(half * 64 + r) * Hh + c);
    }
    __syncthreads();
    if (t < 64) {
      float ss = 0.f;
      #pragma unroll
      for (int i = 0; i < 32; i++) {
        float4 v = *(float4*)&xs[t * 132 + i * 4];
        ss += v.x * v.x + v.y * v.y + v.z * v.z + v.w * v.w;
      }
      float inv = 1.0f / fmaxf(sqrtf(ss), EPS);
      invp[half * 64 + t] = inv;
      sS[half * 64 + t] = sqrtf(inv);
    }
    __syncthreads();
    // transpose + scale + split
    int c = t & 127, rh = t >> 7;
    #pragma unroll
    for (int j = 0; j < 16; j++) {
      int r0 = rh * 32 + 2 * j;
      float v0 = xs[r0 * 132 + c] * sS[half * 64 + r0];
      float v1 = xs[(r0 + 1) * 132 + c] * sS[half * 64 + r0 + 1];
      ushort hh0 = f2bf(v0), hh1 = f2bf(v1);
      ushort ll0 = f2bf(v0 - bf2f(hh0)), ll1 = f2bf(v1 - bf2f(hh1));
      int n = half * 64 + r0;
      ushort2 uh; uh.x = hh0; uh.y = hh1;
      ushort2 ul; ul.x = ll0; ul.y = ll1;
      *(ushort2*)&T[c * 264 + n] = uh;
      *(ushort2*)&T[c * 264 + 128 + n] = ul;
    }
  }
  __syncthreads();

  // GEMM: wave w owns output rows [w*32, w*32+32) x all 128 cols
  int lane = t & 63, w = t >> 6;
  int m = lane & 15, q = lane >> 4;
  f32x4 acc[2][8];
  #pragma unroll
  for (int tr = 0; tr < 2; tr++)
    #pragma unroll
    for (int tc = 0; tc < 8; tc++) acc[tr][tc] = (f32x4){0.f, 0.f, 0.f, 0.f};

  #pragma unroll
  for (int ks = 0; ks < 4; ks++) {
    int n0 = ks * 32 + q * 8;
    bf16x8 Ah[2], Al[2];
    #pragma unroll
    for (int tr = 0; tr < 2; tr++) {
      int cA = w * 32 + tr * 16 + m;
      Ah[tr] = *(bf16x8*)&T[cA * 264 + n0];
      Al[tr] = *(bf16x8*)&T[cA * 264 + 128 + n0];
    }
    #pragma unroll
    for (int tc = 0; tc < 8; tc++) {
      int cB = tc * 16 + m;
      bf16x8 Bh = *(bf16x8*)&T[cB * 264 + n0];
      bf16x8 Bl = *(bf16x8*)&T[cB * 264 + 128 + n0];
      #pragma unroll
      for (int tr = 0; tr < 2; tr++) {
        acc[tr][tc] = MFMA16(Ah[tr], Bh, acc[tr][tc]);
        acc[tr][tc] = MFMA16(Ah[tr], Bl, acc[tr][tc]);
        acc[tr][tc] = MFMA16(Al[tr], Bh, acc[tr][tc]);
      }
    }
  }

  float* outp = Mpart + ((size_t)mb * CCH + chunk) * 16384;
  #pragma unroll
  for (int tr = 0; tr < 2; tr++)
    #pragma unroll
    for (int tc = 0; tc < 8; tc++)
      #pragma unroll
      for (int rg = 0; rg < 4; rg++) {
        int row = w * 32 + tr * 16 + q * 4 + rg;
        int col = tc * 16 + m;
        outp[row * 128 + col] = acc[tr][tc][rg];
      }
}

// ---------------------------------------------------------------------------
// Kernel 3: reduce partials -> Mi[mb][k][hi 0..127 | lo 128..255] (LDS-ready)
// ---------------------------------------------------------------------------
__global__ __launch_bounds__(256) void matr_kernel(const float* __restrict__ Mpart,
                                                   ushort* __restrict__ Mi) {
  int gid = blockIdx.x * 256 + threadIdx.x;   // 16*16384
  int mb = gid >> 14;
  int e = gid & 16383;
  int k = e >> 7, h = e & 127;
  const float* p = Mpart + (size_t)mb * CCH * 16384 + e;
  float s = 0.f;
  #pragma unroll
  for (int c = 0; c < CCH; c++) s += p[(size_t)c * 16384];
  ushort hi = f2bf(s);
  Mi[(size_t)mb * 32768 + k * 256 + h] = hi;
  Mi[(size_t)mb * 32768 + k * 256 + 128 + h] = f2bf(s - bf2f(hi));
}

// ---------------------------------------------------------------------------
// Kernel 4: ygemm — Y = inv * (x @ M), M staged to LDS once per block.
// grid 512 blocks x 64 rows; 4 waves x 16-row tiles; x loaded to registers.
// ---------------------------------------------------------------------------
__global__ __launch_bounds__(256, 2) void ygemm_kernel(const float* __restrict__ h1,
                                                       const float* __restrict__ h2,
                                                       const float* __restrict__ inv,
                                                       const ushort* __restrict__ Mi,
                                                       float* __restrict__ Y) {
  __shared__ ushort Bs[128 * 264];
  __shared__ float invs[64];
  int g0 = blockIdx.x * 64;                   // global row 0..32767
  int which = g0 >> 14, b = (g0 >> 11) & 7, n0 = g0 & 2047;
  const float* xsrc = which ? h2 : h1;
  const ushort* Msrc = Mi + (size_t)((which ^ 1) * 8 + b) * 32768;
  int t = threadIdx.x;
  #pragma unroll
  for (int i = 0; i < 16; i++) {
    int u = t + 256 * i;                      // 0..4095 16B units
    int row = u >> 5, seg = u & 31;
    *(bf16x8*)&Bs[row * 264 + seg * 8] = *(const bf16x8*)&Msrc[u * 8];
  }
  if (t < 64) invs[t] = inv[which * BN + b * Nn + n0 + t];
  __syncthreads();

  int lane = t & 63, m = lane & 15, q = lane >> 4, rb = (t >> 6) * 16;
  const float* xrow = xsrc + ((size_t)b * Nn + n0 + rb + m) * Hh;
  f32x4 acc[8];
  #pragma unroll
  for (int nt = 0; nt < 8; nt++) acc[nt] = (f32x4){0.f, 0.f, 0.f, 0.f};

  #pragma unroll
  for (int ks = 0; ks < 4; ks++) {
    int k0 = ks * 32 + q * 8;
    float xv[8];
    *(float4*)&xv[0] = *(const float4*)(xrow + k0);
    *(float4*)&xv[4] = *(const float4*)(xrow + k0 + 4);
    bf16x8 xh, xl;
    split8(xv, xh, xl);
    #pragma unroll
    for (int nt = 0; nt < 8; nt++) {
      int cB = nt * 16 + m;
      bf16x8 Bh = *(bf16x8*)&Bs[cB * 264 + k0];
      bf16x8 Bl = *(bf16x8*)&Bs[cB * 264 + 128 + k0];
      acc[nt] = MFMA16(xh, Bh, acc[nt]);
      acc[nt] = MFMA16(xh, Bl, acc[nt]);
      acc[nt] = MFMA16(xl, Bh, acc[nt]);
    }
  }

  float* yb = Y + (size_t)g0 * Hh;
  #pragma unroll
  for (int nt = 0; nt < 8; nt++)
    #pragma unroll
    for (int rg = 0; rg < 4; rg++) {
      int row = rb + q * 4 + rg;
      yb[(size_t)row * Hh + nt * 16 + m] = acc[nt][rg] * invs[row];
    }
}

// ---------------------------------------------------------------------------
// Kernel 5: fmk — fm epilogue. W2 staged to LDS once per block; x,y streamed.
// num: 3-pass split; dx2/dy2: 2-pass (positive sums, A-lo negligible).
// ---------------------------------------------------------------------------
__global__ __launch_bounds__(256, 2) void fmk_kernel(const float* __restrict__ h1,
                                                     const float* __restrict__ h2,
                                                     const float* __restrict__ Y,
                                                     const ushort* __restrict__ W2i,
                                                     float* __restrict__ out) {
  __shared__ ushort Ws[128 * 264];
  int g0 = blockIdx.x * 64;
  int which = g0 >> 14, b = (g0 >> 11) & 7, n0 = g0 & 2047;
  const float* xsrc = which ? h2 : h1;
  int t = threadIdx.x;
  #pragma unroll
  for (int i = 0; i < 16; i++) {
    int u = t + 256 * i;
    int row = u >> 5, seg = u & 31;
    *(bf16x8*)&Ws[row * 264 + seg * 8] = *(const bf16x8*)&W2i[u * 8];
  }
  __syncthreads();

  int lane = t & 63, m = lane & 15, q = lane >> 4, rb = (t >> 6) * 16;
  const float* xrow = xsrc + ((size_t)b * Nn + n0 + rb + m) * Hh;
  const float* yrow = Y + (size_t)(g0 + rb + m) * Hh;

  f32x4 aN[8], aX[8], aY[8];
  #pragma unroll
  for (int nt = 0; nt < 8; nt++) {
    aN[nt] = (f32x4){0.f, 0.f, 0.f, 0.f};
    aX[nt] = (f32x4){0.f, 0.f, 0.f, 0.f};
    aY[nt] = (f32x4){0.f, 0.f, 0.f, 0.f};
  }

  #pragma unroll
  for (int ks = 0; ks < 4; ks++) {
    int k0 = ks * 32 + q * 8;
    float xv[8], yv[8], pxy[8], pxx[8], pyy[8];
    *(float4*)&xv[0] = *(const float4*)(xrow + k0);
    *(float4*)&xv[4] = *(const float4*)(xrow + k0 + 4);
    *(float4*)&yv[0] = *(const float4*)(yrow + k0);
    *(float4*)&yv[4] = *(const float4*)(yrow + k0 + 4);
    #pragma unroll
    for (int i = 0; i < 8; i++) {
      pxy[i] = xv[i] * yv[i];
      pxx[i] = xv[i] * xv[i];
      pyy[i] = yv[i] * yv[i];
    }
    bf16x8 xyh, xyl;
    split8(pxy, xyh, xyl);
    bf16x8 xxh = cvt8(pxx);
    bf16x8 yyh = cvt8(pyy);
    #pragma unroll
    for (int nt = 0; nt < 8; nt++) {
      int cB = nt * 16 + m;
      bf16x8 wh = *(bf16x8*)&Ws[cB * 264 + k0];
      bf16x8 wl = *(bf16x8*)&Ws[cB * 264 + 128 + k0];
      aN[nt] = MFMA16(xyh, wh, aN[nt]);
      aN[nt] = MFMA16(xyh, wl, aN[nt]);
      aN[nt] = MFMA16(xyl, wh, aN[nt]);
      aX[nt] = MFMA16(xxh, wh, aX[nt]);
      aX[nt] = MFMA16(xxh, wl, aX[nt]);
      aY[nt] = MFMA16(yyh, wh, aY[nt]);
      aY[nt] = MFMA16(yyh, wl, aY[nt]);
    }
  }

  float* ob = out + (size_t)g0 * Hh;
  #pragma unroll
  for (int nt = 0; nt < 8; nt++)
    #pragma unroll
    for (int rg = 0; rg < 4; rg++) {
      int row = rb + q * 4 + rg;
      float dx = fmaxf(sqrtf(fmaxf(aX[nt][rg], 0.f)), EPS);
      float dy = fmaxf(sqrtf(fmaxf(aY[nt][rg], 0.f)), EPS);
      ob[(size_t)row * Hh + nt * 16 + m] = aN[nt][rg] / (dx * dy);
    }
}

// ---------------------------------------------------------------------------
extern "C" void kernel_launch(void* const* d_in, const int* in_sizes, int n_in,
                              void* d_out, int out_size, void* d_ws, size_t ws_size,
                              hipStream_t stream) {
  const float* h1 = (const float*)d_in[0];
  const float* h2 = (const float*)d_in[1];
  const float* wm = (const float*)d_in[2];
  float* out = (float*)d_out;

  char* ws = (char*)d_ws;
  float* inv   = (float*)ws;                         // 2*16384*4   = 131072 B
  ushort* W2i  = (ushort*)(ws + 131072);             // 32768*2     = 65536 B
  ushort* Mi   = (ushort*)(ws + 196608);             // 16*32768*2  = 1 MiB
  float* Mpart = (float*)(ws + 1245184);             // 16*16*16384*4 = 16 MiB
  float* Y     = (float*)(ws + 1245184 + 16777216);  // 32768*128*4 = 16 MiB

  w2i_kernel<<<Hh * Hh / 256, 256, 0, stream>>>(wm, W2i);
  matp_kernel<<<16 * CCH, 256, 0, stream>>>(h1, h2, inv, Mpart);
  matr_kernel<<<16 * 16384 / 256, 256, 0, stream>>>(Mpart, Mi);
  ygemm_kernel<<<2 * BN / 64, 256, 0, stream>>>(h1, h2, inv, Mi, Y);
  fmk_kernel<<<2 * BN / 64, 256, 0, stream>>>(h1, h2, Y, W2i, out);
}

// Round 5
// 100.393 us; speedup vs baseline: 2.5780x; 1.0740x over previous
//
#include <hip/hip_runtime.h>
#include <hip/hip_bf16.h>
#include <math.h>

#define EPS 1e-8f

constexpr int Bb = 8, Nn = 2048, Hh = 128;
constexpr int BN = Bb * Nn;      // 16384 rows per tensor
constexpr int CCH = 16;          // split-K chunks for matp

typedef __attribute__((ext_vector_type(8))) short bf16x8;
typedef __attribute__((ext_vector_type(4))) float f32x4;

#define MFMA16(a, b, c) __builtin_amdgcn_mfma_f32_16x16x32_bf16(a, b, c, 0, 0, 0)

static __device__ __forceinline__ ushort f2bf(float f) {
  union { __hip_bfloat16 h; ushort s; } u;
  u.h = __float2bfloat16(f);   // RNE
  return u.s;
}
static __device__ __forceinline__ float bf2f(ushort s) {
  union { float f; uint u; } u;
  u.u = ((uint)s) << 16;
  return u.f;
}
static __device__ __forceinline__ bf16x8 cvt8(const float* v) {
  bf16x8 r;
  #pragma unroll
  for (int i = 0; i < 4; i++) {
    union { __hip_bfloat162 h; short2 s; } u;
    u.h = __float22bfloat162_rn(make_float2(v[2 * i], v[2 * i + 1]));
    r[2 * i] = u.s.x; r[2 * i + 1] = u.s.y;
  }
  return r;
}
static __device__ __forceinline__ void split8(const float* v, bf16x8& hi, bf16x8& lo) {
  hi = cvt8(v);
  float res[8];
  #pragma unroll
  for (int i = 0; i < 8; i++) res[i] = v[i] - bf2f((ushort)hi[i]);
  lo = cvt8(res);
}

// ---------------------------------------------------------------------------
// Kernel 1: matp — M = (s.h)^T (s.h) per (mat,b), split-K chunk of 128 rows.
// Computes inv inline, builds transposed split-bf16 T in LDS, 3-pass MFMA,
// fp32 partials. grid: idx = mb*CCH + chunk, mb = mat*8+b.
// ---------------------------------------------------------------------------
__global__ __launch_bounds__(256) void matp_kernel(const float* __restrict__ h1,
                                                   const float* __restrict__ h2,
                                                   float* __restrict__ inv_out,
                                                   float* __restrict__ Mpart) {
  int idx = blockIdx.x;
  int chunk = idx % CCH;
  int mb = idx / CCH;
  int b = mb & 7;
  int mat = mb >> 3;
  const float* src = (mat ? h2 : h1) + ((size_t)b * Nn + chunk * 128) * Hh;
  float* invp = inv_out + mat * BN + b * Nn + chunk * 128;

  __shared__ float xs[64 * 132];     // 64-row staging, padded
  __shared__ ushort T[128 * 264];    // [col c][hi n 0..127 | lo n 128..255 | pad]
  __shared__ float sS[128];          // sqrt(inv) per row
  int t = threadIdx.x;

  for (int half = 0; half < 2; half++) {
    __syncthreads();
    #pragma unroll
    for (int i = 0; i < 8; i++) {
      int u = t + 256 * i;                 // 0..2047 float4 units
      int r = u >> 5, c = (u & 31) << 2;
      *(float4*)&xs[r * 132 + c] = *(const float4*)(src + (size_t)(half * 64 + r) * Hh + c);
    }
    __syncthreads();
    if (t < 64) {
      float ss = 0.f;
      #pragma unroll
      for (int i = 0; i < 32; i++) {
        float4 v = *(float4*)&xs[t * 132 + i * 4];
        ss += v.x * v.x + v.y * v.y + v.z * v.z + v.w * v.w;
      }
      float inv = 1.0f / fmaxf(sqrtf(ss), EPS);
      invp[half * 64 + t] = inv;
      sS[half * 64 + t] = sqrtf(inv);
    }
    __syncthreads();
    // transpose + scale + split
    int c = t & 127, rh = t >> 7;
    #pragma unroll
    for (int j = 0; j < 16; j++) {
      int r0 = rh * 32 + 2 * j;
      float v0 = xs[r0 * 132 + c] * sS[half * 64 + r0];
      float v1 = xs[(r0 + 1) * 132 + c] * sS[half * 64 + r0 + 1];
      ushort hh0 = f2bf(v0), hh1 = f2bf(v1);
      ushort ll0 = f2bf(v0 - bf2f(hh0)), ll1 = f2bf(v1 - bf2f(hh1));
      int n = half * 64 + r0;
      ushort2 uh; uh.x = hh0; uh.y = hh1;
      ushort2 ul; ul.x = ll0; ul.y = ll1;
      *(ushort2*)&T[c * 264 + n] = uh;
      *(ushort2*)&T[c * 264 + 128 + n] = ul;
    }
  }
  __syncthreads();

  // GEMM: wave w owns output rows [w*32, w*32+32) x all 128 cols
  int lane = t & 63, w = t >> 6;
  int m = lane & 15, q = lane >> 4;
  f32x4 acc[2][8];
  #pragma unroll
  for (int tr = 0; tr < 2; tr++)
    #pragma unroll
    for (int tc = 0; tc < 8; tc++) acc[tr][tc] = (f32x4){0.f, 0.f, 0.f, 0.f};

  #pragma unroll
  for (int ks = 0; ks < 4; ks++) {
    int n0 = ks * 32 + q * 8;
    bf16x8 Ah[2], Al[2];
    #pragma unroll
    for (int tr = 0; tr < 2; tr++) {
      int cA = w * 32 + tr * 16 + m;
      Ah[tr] = *(bf16x8*)&T[cA * 264 + n0];
      Al[tr] = *(bf16x8*)&T[cA * 264 + 128 + n0];
    }
    #pragma unroll
    for (int tc = 0; tc < 8; tc++) {
      int cB = tc * 16 + m;
      bf16x8 Bh = *(bf16x8*)&T[cB * 264 + n0];
      bf16x8 Bl = *(bf16x8*)&T[cB * 264 + 128 + n0];
      #pragma unroll
      for (int tr = 0; tr < 2; tr++) {
        acc[tr][tc] = MFMA16(Ah[tr], Bh, acc[tr][tc]);
        acc[tr][tc] = MFMA16(Ah[tr], Bl, acc[tr][tc]);
        acc[tr][tc] = MFMA16(Al[tr], Bh, acc[tr][tc]);
      }
    }
  }

  float* outp = Mpart + ((size_t)mb * CCH + chunk) * 16384;
  #pragma unroll
  for (int tr = 0; tr < 2; tr++)
    #pragma unroll
    for (int tc = 0; tc < 8; tc++)
      #pragma unroll
      for (int rg = 0; rg < 4; rg++) {
        int row = w * 32 + tr * 16 + q * 4 + rg;
        int col = tc * 16 + m;
        outp[row * 128 + col] = acc[tr][tc][rg];
      }
}

// ---------------------------------------------------------------------------
// Kernel 2: reduce partials -> Mi[mb][k][hi 0..127 | lo 128..255] (LDS-ready)
// ---------------------------------------------------------------------------
__global__ __launch_bounds__(256) void matr_kernel(const float* __restrict__ Mpart,
                                                   ushort* __restrict__ Mi) {
  int gid = blockIdx.x * 256 + threadIdx.x;   // 16*16384
  int mb = gid >> 14;
  int e = gid & 16383;
  int k = e >> 7, h = e & 127;
  const float* p = Mpart + (size_t)mb * CCH * 16384 + e;
  float s = 0.f;
  #pragma unroll
  for (int c = 0; c < CCH; c++) s += p[(size_t)c * 16384];
  ushort hi = f2bf(s);
  Mi[(size_t)mb * 32768 + k * 256 + h] = hi;
  Mi[(size_t)mb * 32768 + k * 256 + 128 + h] = f2bf(s - bf2f(hi));
}

// ---------------------------------------------------------------------------
// Kernel 3: fused2 — phase 1: y = inv*(x@M) with Mi in LDS, x in registers;
// phase 2: re-stage LDS with W2 (computed from wm in-kernel), fm epilogue.
// 128 rows/block, 512 threads (8 waves x 16 rows), 256 blocks = 1/CU.
// LDS: T 67.6 KB + ys 67.6 KB + invs = 135.7 KB (< 160 KB).
// ---------------------------------------------------------------------------
__global__ __launch_bounds__(512, 2) void fused2_kernel(
    const float* __restrict__ h1, const float* __restrict__ h2,
    const float* __restrict__ inv, const ushort* __restrict__ Mi,
    const float* __restrict__ wm, float* __restrict__ out) {
  __shared__ ushort T[128 * 264];    // B-matrix: [row][hi 0..127 | lo 128..255]
  __shared__ float ys[128 * 132];
  __shared__ float invs[128];

  int g0 = blockIdx.x * 128;         // global row 0..32767
  int which = g0 >> 14, b = (g0 >> 11) & 7, n0 = g0 & 2047;
  const float* xsrc = which ? h2 : h1;
  const ushort* Msrc = Mi + (size_t)((which ^ 1) * 8 + b) * 32768;
  int t = threadIdx.x;

  // stage Mi -> T
  #pragma unroll
  for (int i = 0; i < 8; i++) {
    int u = t + 512 * i;             // 0..4095 16B units
    int row = u >> 5, seg = u & 31;
    *(bf16x8*)&T[row * 264 + seg * 8] = *(const bf16x8*)&Msrc[u * 8];
  }
  if (t < 128) invs[t] = inv[which * BN + b * Nn + n0 + t];
  __syncthreads();

  int lane = t & 63, m = lane & 15, q = lane >> 4, rb = (t >> 6) * 16;
  const float* xrow = xsrc + ((size_t)b * Nn + n0 + rb + m) * Hh;

  // x into registers, kept across both phases
  float xv[4][8];
  #pragma unroll
  for (int ks = 0; ks < 4; ks++) {
    int k0 = ks * 32 + q * 8;
    *(float4*)&xv[ks][0] = *(const float4*)(xrow + k0);
    *(float4*)&xv[ks][4] = *(const float4*)(xrow + k0 + 4);
  }

  // ---- phase 1: y = (x @ M) * inv ----
  {
    f32x4 acc[8];
    #pragma unroll
    for (int nt = 0; nt < 8; nt++) acc[nt] = (f32x4){0.f, 0.f, 0.f, 0.f};
    #pragma unroll
    for (int ks = 0; ks < 4; ks++) {
      int k0 = ks * 32 + q * 8;
      bf16x8 xh, xl;
      split8(xv[ks], xh, xl);
      #pragma unroll
      for (int nt = 0; nt < 8; nt++) {
        int cB = nt * 16 + m;
        bf16x8 Bh = *(bf16x8*)&T[cB * 264 + k0];
        bf16x8 Bl = *(bf16x8*)&T[cB * 264 + 128 + k0];
        acc[nt] = MFMA16(xh, Bh, acc[nt]);
        acc[nt] = MFMA16(xh, Bl, acc[nt]);
        acc[nt] = MFMA16(xl, Bh, acc[nt]);
      }
    }
    // C-layout -> ys (rows are wave-private; no cross-wave hazard)
    #pragma unroll
    for (int nt = 0; nt < 8; nt++)
      #pragma unroll
      for (int rg = 0; rg < 4; rg++) {
        int row = rb + q * 4 + rg;
        ys[row * 132 + nt * 16 + m] = acc[nt][rg] * invs[row];
      }
  }
  __syncthreads();   // everyone done reading T(Mi)

  // re-stage T with W2 = wm^2 (hi/lo split), computed in-kernel
  #pragma unroll
  for (int i = 0; i < 16; i++) {
    int u = t + 512 * i;             // pair id 0..8191
    int r = u >> 6, c = (u & 63) * 2;
    float2 w2 = *(const float2*)(wm + r * 128 + c);
    float v0 = w2.x * w2.x, v1 = w2.y * w2.y;
    ushort hh0 = f2bf(v0), hh1 = f2bf(v1);
    ushort ll0 = f2bf(v0 - bf2f(hh0)), ll1 = f2bf(v1 - bf2f(hh1));
    ushort2 uh; uh.x = hh0; uh.y = hh1;
    ushort2 ul; ul.x = ll0; ul.y = ll1;
    *(ushort2*)&T[r * 264 + c] = uh;
    *(ushort2*)&T[r * 264 + 128 + c] = ul;
  }
  __syncthreads();

  // ---- phase 2: fm epilogue ----
  f32x4 aN[8], aX[8], aY[8];
  #pragma unroll
  for (int nt = 0; nt < 8; nt++) {
    aN[nt] = (f32x4){0.f, 0.f, 0.f, 0.f};
    aX[nt] = (f32x4){0.f, 0.f, 0.f, 0.f};
    aY[nt] = (f32x4){0.f, 0.f, 0.f, 0.f};
  }

  #pragma unroll
  for (int ks = 0; ks < 4; ks++) {
    int k0 = ks * 32 + q * 8;
    float yv[8], pxy[8], pxx[8], pyy[8];
    *(float4*)&yv[0] = *(const float4*)&ys[(rb + m) * 132 + k0];
    *(float4*)&yv[4] = *(const float4*)&ys[(rb + m) * 132 + k0 + 4];
    #pragma unroll
    for (int i = 0; i < 8; i++) {
      float xf = xv[ks][i];
      pxy[i] = xf * yv[i];
      pxx[i] = xf * xf;
      pyy[i] = yv[i] * yv[i];
    }
    bf16x8 xyh, xyl;
    split8(pxy, xyh, xyl);
    bf16x8 xxh = cvt8(pxx);
    bf16x8 yyh = cvt8(pyy);
    #pragma unroll
    for (int nt = 0; nt < 8; nt++) {
      int cB = nt * 16 + m;
      bf16x8 wh = *(bf16x8*)&T[cB * 264 + k0];
      bf16x8 wl = *(bf16x8*)&T[cB * 264 + 128 + k0];
      aN[nt] = MFMA16(xyh, wh, aN[nt]);
      aN[nt] = MFMA16(xyh, wl, aN[nt]);
      aN[nt] = MFMA16(xyl, wh, aN[nt]);
      aX[nt] = MFMA16(xxh, wh, aX[nt]);
      aX[nt] = MFMA16(xxh, wl, aX[nt]);
      aY[nt] = MFMA16(yyh, wh, aY[nt]);
      aY[nt] = MFMA16(yyh, wl, aY[nt]);
    }
  }

  float* ob = out + (size_t)g0 * Hh;
  #pragma unroll
  for (int nt = 0; nt < 8; nt++)
    #pragma unroll
    for (int rg = 0; rg < 4; rg++) {
      int row = rb + q * 4 + rg;
      float dx = fmaxf(sqrtf(fmaxf(aX[nt][rg], 0.f)), EPS);
      float dy = fmaxf(sqrtf(fmaxf(aY[nt][rg], 0.f)), EPS);
      ob[(size_t)row * Hh + nt * 16 + m] = aN[nt][rg] / (dx * dy);
    }
}

// ---------------------------------------------------------------------------
extern "C" void kernel_launch(void* const* d_in, const int* in_sizes, int n_in,
                              void* d_out, int out_size, void* d_ws, size_t ws_size,
                              hipStream_t stream) {
  const float* h1 = (const float*)d_in[0];
  const float* h2 = (const float*)d_in[1];
  const float* wm = (const float*)d_in[2];
  float* out = (float*)d_out;

  char* ws = (char*)d_ws;
  float* inv   = (float*)ws;                 // 2*16384*4    = 131072 B
  ushort* Mi   = (ushort*)(ws + 131072);     // 16*32768*2   = 1 MiB
  float* Mpart = (float*)(ws + 1179648);     // 16*16*16384*4 = 16 MiB

  matp_kernel<<<16 * CCH, 256, 0, stream>>>(h1, h2, inv, Mpart);
  matr_kernel<<<16 * 16384 / 256, 256, 0, stream>>>(Mpart, Mi);
  fused2_kernel<<<2 * BN / 128, 512, 0, stream>>>(h1, h2, inv, Mi, wm, out);
}